// Round 10
// baseline (283.571 us; speedup 1.0000x reference)
//
#include <hip/hip_runtime.h>
#include <hip/hip_bf16.h>
#include <hip/hip_cooperative_groups.h>

namespace cg = cooperative_groups;

// ---------------- problem constants ----------------
#define E_    8
#define TT    4096      // tokens = B*S
#define DD    512
#define HH    2048
#define CAP   1075      // round(2*4096*1.05/8)
#define MPAD  1152      // 9 * 128, padded rows per expert
#define MT    9         // 128-row M tiles per expert (gemm1)
#define MT2   18        // 64-row M tiles per expert (gemm2)

typedef __bf16 bf16_t;
typedef bf16_t bf16x4 __attribute__((ext_vector_type(4)));
typedef bf16_t bf16x8 __attribute__((ext_vector_type(8)));
typedef float  f32x4  __attribute__((ext_vector_type(4)));
typedef unsigned int u32;

__device__ __forceinline__ bf16_t tobf(float f) { return (bf16_t)f; }  // fptrunc, RNE

// tanh-form gelu: max |diff vs erf-gelu| ~3e-4 in h; through fc2's random-sign
// weights adds ~2e-4 to y (threshold 4.97e-2). exp overflow-safe via |u|+copysign.
__device__ __forceinline__ float gelu_f(float v) {
  const float u = v * (0.7978845608028654f + 0.035677408136300125f * v * v);
  const float a = __builtin_fabsf(u);
  const float ex = __expf(2.0f * a);
  float th = 1.0f - 2.0f / (ex + 1.0f);
  th = __builtin_copysignf(th, u);
  return 0.5f * v * (1.0f + th);
}

// ---------------- workspace layout (bytes) ----------------
// hdr: imp[8] f32 @0, kept[8] i32 @64
#define OFF_TOPI  256u
#define OFF_TOPG  (OFF_TOPI + 4096u*2u*4u)
#define OFF_SLOT  (OFF_TOPG + 4096u*2u*4u)            // slot_map[2*T] i32
#define OFF_ETOK  (OFF_SLOT + 4096u*2u*4u)
#define OFF_EWT   (OFF_ETOK + 8u*1152u*4u)
#define OFF_XG    (OFF_EWT  + 8u*1152u*4u)            // 16B aligned
#define XG_BYTES  (8u*1152u*512u*2u)                  // 9,437,184
#define OFF_W1T   (OFF_XG + XG_BYTES)
#define W1T_BYTES (8u*512u*2048u*2u)                  // 16,777,216
#define OFF_W2T   (OFF_W1T + W1T_BYTES)
#define W2T_BYTES (8u*2048u*512u*2u)                  // 16,777,216
#define OFF_H     (OFF_W2T + W2T_BYTES)
#define H_BYTES   (8u*1152u*2048u*2u)                 // 37,748,736
// Ybuf bf16 [E][MPAD][DD] = 9,437,184 B ALIASES Xg (dead after gemm1).
#define OFF_Y     OFF_XG
// total ~80.9 MB

// ---------------- prep v3 (cooperative, 256 blocks x 1024 threads) ------------
// FULL-DEVICE grid (r6's failure: 64 blocks = 25% of CUs; r7's failure:
// barrier-serialized transpose phase inside — both removed).
// Phase 1: router, 1 token/wave (4096 waves — same parallelism as standalone).
// Phase 2: capacity scan on block 0 (exact slot-major semantics).
// Phase 3: gather, 3 rows/wave. Saves 2 launch boundaries + 2 kernel ramps.
__global__ __launch_bounds__(1024) void prep_kernel(
    const float* __restrict__ x, const float* __restrict__ gw,
    float* __restrict__ imp, int* __restrict__ top_i, float* __restrict__ top_g,
    int* __restrict__ etok, float* __restrict__ ewt, int* __restrict__ slot_map,
    int* __restrict__ kept, float* __restrict__ scal, bf16_t* __restrict__ Xg) {
  const int tid = threadIdx.x, bid = blockIdx.x;
  const int wave = tid >> 6, lane = tid & 63;
  __shared__ float simp[16][E_];
  __shared__ u32 wt16[16][4];

  // ---- phase 1: router, one token per wave ----
  {
    const int t = bid * 16 + wave;
    float p[E_];
#pragma unroll
    for (int e = 0; e < E_; ++e) p[e] = 0.f;
    const float* xr = x + (size_t)t * DD;
#pragma unroll
    for (int it = 0; it < DD / 64; ++it) {
      const int d = it * 64 + lane;
      const float xv = xr[d];
#pragma unroll
      for (int e = 0; e < E_; ++e) p[e] += xv * gw[e * DD + d];
    }
#pragma unroll
    for (int off = 32; off > 0; off >>= 1) {
#pragma unroll
      for (int e = 0; e < E_; ++e) p[e] += __shfl_down(p[e], off);
    }
    if (lane == 0) {
      float mx = p[0];
#pragma unroll
      for (int e = 1; e < E_; ++e) mx = fmaxf(mx, p[e]);
      float g[E_]; float s = 0.f;
#pragma unroll
      for (int e = 0; e < E_; ++e) { g[e] = expf(p[e] - mx); s += g[e]; }
      const float inv = 1.f / s;
#pragma unroll
      for (int e = 0; e < E_; ++e) { g[e] *= inv; simp[wave][e] = g[e]; }
      // top-2, ties -> lowest index (matches jax.lax.top_k)
      int i0 = 0;
#pragma unroll
      for (int e = 1; e < E_; ++e) if (g[e] > g[i0]) i0 = e;
      int i1 = (i0 == 0) ? 1 : 0;
#pragma unroll
      for (int e = 0; e < E_; ++e) if (e != i0 && g[e] > g[i1]) i1 = e;
      top_i[t * 2 + 0] = i0;  top_i[t * 2 + 1] = i1;
      top_g[t * 2 + 0] = g[i0]; top_g[t * 2 + 1] = g[i1];
    }
    __syncthreads();
    if (tid < E_) {
      float s = 0.f;
#pragma unroll
      for (int w = 0; w < 16; ++w) s += simp[w][tid];
      atomicAdd(&imp[tid], s);   // device-scope
    }
  }
  cg::this_grid().sync();

  // ---- phase 2: capacity scan (block 0 only; block-uniform branch) ----
  if (bid == 0) {
    int eidx[8];
#pragma unroll
    for (int q = 0; q < 8; ++q) {
      const int j = tid * 8 + q;          // slot-major: j = k*T + t
      const int k = j >> 12, t = j & (TT - 1);
      eidx[q] = top_i[t * 2 + k];
    }
    u32 pk[4] = {0u, 0u, 0u, 0u};
#pragma unroll
    for (int q = 0; q < 8; ++q) pk[eidx[q] >> 1] += 1u << ((eidx[q] & 1) * 16);

    u32 v[4] = {pk[0], pk[1], pk[2], pk[3]};   // inclusive wave scan
#pragma unroll
    for (int off = 1; off < 64; off <<= 1) {
#pragma unroll
      for (int p = 0; p < 4; ++p) {
        const u32 n = (u32)__shfl_up((int)v[p], off);
        if (lane >= off) v[p] += n;
      }
    }
    if (lane == 63) {
#pragma unroll
      for (int p = 0; p < 4; ++p) wt16[wave][p] = v[p];
    }
    __syncthreads();
    u32 base[4] = {0u, 0u, 0u, 0u}, tot[4] = {0u, 0u, 0u, 0u};
#pragma unroll
    for (int w = 0; w < 16; ++w) {
#pragma unroll
      for (int p = 0; p < 4; ++p) {
        const u32 xv = wt16[w][p];
        if (w < wave) base[p] += xv;
        tot[p] += xv;
      }
    }
    int run[E_];
#pragma unroll
    for (int p = 0; p < 4; ++p) {
      const u32 excl = base[p] + v[p] - pk[p];    // exclusive thread prefix
      run[2 * p]     = (int)(excl & 0xFFFFu);
      run[2 * p + 1] = (int)(excl >> 16);
    }
#pragma unroll
    for (int q = 0; q < 8; ++q) {
      const int e = eidx[q];
      const int pos = run[e]++;           // counts ALL earlier same-expert entries
      const int j = tid * 8 + q;
      if (pos < CAP) {
        const int k = j >> 12, t = j & (TT - 1);
        etok[e * MPAD + pos] = t;
        ewt[e * MPAD + pos] = top_g[t * 2 + k];
        slot_map[j] = (e << 16) | pos;
      } else {
        slot_map[j] = -1;
      }
    }
    if (tid == 0) {
      float tpe[E_];
#pragma unroll
      for (int p = 0; p < 4; ++p) {
        const int t0 = (int)(tot[p] & 0xFFFFu), t1 = (int)(tot[p] >> 16);
        const int k0 = t0 < CAP ? t0 : CAP, k1 = t1 < CAP ? t1 : CAP;
        kept[2 * p] = k0; kept[2 * p + 1] = k1;
        tpe[2 * p] = (float)k0; tpe[2 * p + 1] = (float)k1;
      }
      float ms = 0.f;
#pragma unroll
      for (int e = 0; e < E_; ++e) ms += tpe[e];
      ms *= (1.f / E_);
      float vt = 0.f;
#pragma unroll
      for (int e = 0; e < E_; ++e) { const float d = tpe[e] - ms; vt += d * d; }
      vt *= (1.f / E_);
      const float ll = vt / ((ms + 1e-6f) * (ms + 1e-6f));

      float iv[E_], mi = 0.f;
#pragma unroll
      for (int e = 0; e < E_; ++e) { iv[e] = imp[e]; mi += iv[e]; }
      mi *= (1.f / E_);
      float vi = 0.f;
#pragma unroll
      for (int e = 0; e < E_; ++e) { const float d = iv[e] - mi; vi += d * d; }
      vi *= (1.f / E_);
      const float il = vi / ((mi + 1e-6f) * (mi + 1e-6f));

      scal[0] = 0.5f * (il + ll);   // l_aux
      scal[1] = ll;                 // l_load
    }
  }
  cg::this_grid().sync();

  // ---- phase 3: gather, 3 rows/wave over 4096 waves (9216 rows) ----
  // Pad rows (m >= kept[e]) stay 0xAA poison: finite bf16; outputs from them
  // are discarded (gemm2 epilogue guard + combine touches kept slots only).
#pragma unroll
  for (int i = 0; i < 3; ++i) {
    const int rw = i * 4096 + bid * 16 + wave;
    if (rw < E_ * MPAD) {
      const int e = rw / MPAD, m = rw % MPAD;
      if (m < kept[e]) {
        const int t = etok[e * MPAD + m];
        const float* src = x + (size_t)t * DD + lane * 8;
        const float4 a = *(const float4*)src;
        const float4 b = *(const float4*)(src + 4);
        bf16_t tmp[8] = {tobf(a.x), tobf(a.y), tobf(a.z), tobf(a.w),
                         tobf(b.x), tobf(b.y), tobf(b.z), tobf(b.w)};
        *(bf16x8*)(Xg + ((size_t)e * MPAD + m) * DD + lane * 8) = *(const bf16x8*)tmp;
      }
    }
  }
}

// ---------------- merged weight transpose+cast, vectorized stores -------------
// 64x64 f32 tile -> bf16x4 (8B) packed stores. LDS 64x65 pad (2-way = free).
// z<8: fc1 [512][2048]->[2048][512]; z>=8: fc2 [2048][512]->[512][2048].
__global__ __launch_bounds__(256) void transpose_both_kernel(
    const float* __restrict__ fc1, bf16_t* __restrict__ w1t,
    const float* __restrict__ fc2, bf16_t* __restrict__ w2t) {
  __shared__ float tile[64][65];
  const int z = blockIdx.z;
  const bool first = (z < 8);
  const int e = first ? z : z - 8;
  const int R = first ? DD : HH;
  const int C = first ? HH : DD;
  const int ct = first ? blockIdx.x : blockIdx.y;   // C/64 tiles
  const int rt = first ? blockIdx.y : blockIdx.x;   // R/64 tiles
  const float* ip = (first ? fc1 : fc2) + (size_t)e * DD * HH;
  bf16_t* op = (first ? w1t : w2t) + (size_t)e * DD * HH;
  const int r0 = rt * 64, c0 = ct * 64;
  const int tid = threadIdx.x;
  const int rr = tid >> 6, cc = tid & 63;           // read: 4 rows/pass, 64 cols
#pragma unroll
  for (int p = 0; p < 16; ++p)
    tile[p * 4 + rr][cc] = ip[(size_t)(r0 + p * 4 + rr) * C + c0 + cc];
  __syncthreads();
  const int g = tid & 15, ob = tid >> 4;            // write: col-group, row-base
#pragma unroll
  for (int p = 0; p < 4; ++p) {
    const int oc = p * 16 + ob;
    bf16x4 o4;
    o4.x = tobf(tile[g * 4 + 0][oc]);
    o4.y = tobf(tile[g * 4 + 1][oc]);
    o4.z = tobf(tile[g * 4 + 2][oc]);
    o4.w = tobf(tile[g * 4 + 3][oc]);
    *(bf16x4*)(op + (size_t)(c0 + oc) * R + r0 + g * 4) = o4;
  }
}

// ---------------- TN GEMM core (r8, proven): C^T via swapped MFMA operands ----
// A: [MI*32 rows][KSTR] bf16, B: [128 cols][KSTR] bf16 (pre-transposed).
// acc[j][i] = mfma(bfr[j], af[i], acc) -> transposed tile: lane&15 -> m,
// quad*4+reg -> n, so each thread owns 4 CONSECUTIVE n -> packed stores.
// Both operands staged via global_load_lds (coalesced); LDS 16B-chunk XOR
// swizzle on the GLOBAL-side address; read side XORs chunk with l15&7.
// NOTE (r9): A fragments direct from global = 1KB-stride lane gather = 2x
// regression. A must round-trip through LDS.
template <int MI, int KLEN, int KSTR>
__device__ __forceinline__ void gemm_core(
    const bf16_t* __restrict__ A, const bf16_t* __restrict__ B,
    bf16_t* As, bf16_t* Bs, f32x4 (&acc)[4][MI]) {
  const int tid = threadIdx.x;
  const int wave = tid >> 6, lane = tid & 63;
  const int r8 = lane >> 3;                       // row within 8-row group
  const int kswz = ((lane & 7) ^ r8) * 8;         // swizzled k-offset (elements)
  const bf16_t* ga = A + (size_t)(wave * (MI * 8) + r8) * KSTR + kswz;
  const bf16_t* gb = B + (size_t)(wave * 32 + r8) * KSTR + kswz;
  const int mw = (wave >> 1) * (MI * 16), nw = (wave & 1) * 64;
  const int l15 = lane & 15, quad = lane >> 4;
  const int sw = l15 & 7;                         // read-side swizzle key

  for (int k0 = 0; k0 < KLEN; k0 += 64) {
    __syncthreads();   // protect LDS from overwrite while prior chunk computes
#pragma unroll
    for (int p = 0; p < MI; ++p) {
      __builtin_amdgcn_global_load_lds(
          (const __attribute__((address_space(1))) void*)(ga + (size_t)p * 8 * KSTR + k0),
          (__attribute__((address_space(3))) void*)(As + (wave * (MI * 8) + p * 8) * 64),
          16, 0, 0);
    }
#pragma unroll
    for (int p = 0; p < 4; ++p) {
      __builtin_amdgcn_global_load_lds(
          (const __attribute__((address_space(1))) void*)(gb + (size_t)p * 8 * KSTR + k0),
          (__attribute__((address_space(3))) void*)(Bs + (wave * 32 + p * 8) * 64),
          16, 0, 0);
    }
    __syncthreads();   // drains vmcnt before compute
#pragma unroll
    for (int ks = 0; ks < 2; ++ks) {
      bf16x8 af[MI], bfr[4];
#pragma unroll
      for (int i = 0; i < MI; ++i)
        af[i] = *(const bf16x8*)(As + (mw + i * 16 + l15) * 64 + (((ks * 4 + quad) ^ sw) << 3));
#pragma unroll
      for (int j = 0; j < 4; ++j)
        bfr[j] = *(const bf16x8*)(Bs + (nw + j * 16 + l15) * 64 + (((ks * 4 + quad) ^ sw) << 3));
#pragma unroll
      for (int j = 0; j < 4; ++j)
#pragma unroll
        for (int i = 0; i < MI; ++i)
          acc[j][i] = __builtin_amdgcn_mfma_f32_16x16x32_bf16(bfr[j], af[i], acc[j][i], 0, 0, 0);
    }
  }
}

// ---------------- GEMM1: H = gelu(Xg @ W1 + b1), bf16 out, 128x128 tile ------
// blockIdx.x = expert -> XCD (id%8): each XCD's window touches one expert's
// B tiles (~2 MB, L2-resident; verified FETCH 46->21 MB in r5).
__global__ __launch_bounds__(256, 4) void gemm1_kernel(
    const bf16_t* __restrict__ Xg, const bf16_t* __restrict__ W1t,
    const float* __restrict__ b1, bf16_t* __restrict__ Hbuf) {
  __shared__ __align__(16) bf16_t As[128 * 64];
  __shared__ __align__(16) bf16_t Bs[128 * 64];
  const int e = blockIdx.x, tileN = blockIdx.y, tileM = blockIdx.z;
  const bf16_t* A = Xg + ((size_t)e * MPAD + tileM * 128) * DD;
  const bf16_t* B = W1t + ((size_t)e * HH + tileN * 128) * DD;
  f32x4 acc[4][4];
  const f32x4 z = {0.f, 0.f, 0.f, 0.f};
#pragma unroll
  for (int j = 0; j < 4; ++j)
#pragma unroll
    for (int i = 0; i < 4; ++i) acc[j][i] = z;
  gemm_core<4, DD, DD>(A, B, As, Bs, acc);

  const int tid = threadIdx.x, wave = tid >> 6, lane = tid & 63;
  const int mw = (wave >> 1) * 64, nw = (wave & 1) * 64;
  const int l15 = lane & 15, quad = lane >> 4;
#pragma unroll
  for (int j = 0; j < 4; ++j) {
    const int n0 = tileN * 128 + nw + j * 16 + quad * 4;   // 4 consecutive n
    const float4 b4 = *(const float4*)(b1 + e * HH + n0);
#pragma unroll
    for (int i = 0; i < 4; ++i) {
      const int m = tileM * 128 + mw + i * 16 + l15;
      bf16x4 h4;
      h4.x = tobf(gelu_f(acc[j][i][0] + b4.x));
      h4.y = tobf(gelu_f(acc[j][i][1] + b4.y));
      h4.z = tobf(gelu_f(acc[j][i][2] + b4.z));
      h4.w = tobf(gelu_f(acc[j][i][3] + b4.w));
      *(bf16x4*)(Hbuf + ((size_t)e * MPAD + m) * HH + n0) = h4;   // 8B store
    }
  }
}

// ---------------- GEMM2: Ybuf = H @ W2 (bf16 out), 64x128 tile ---------------
__global__ __launch_bounds__(256, 6) void gemm2_kernel(
    const bf16_t* __restrict__ Hbuf, const bf16_t* __restrict__ W2t,
    const int* __restrict__ kept, bf16_t* __restrict__ Ybuf) {
  __shared__ __align__(16) bf16_t As[64 * 64];    // 8 KB
  __shared__ __align__(16) bf16_t Bs[128 * 64];   // 16 KB
  const int e = blockIdx.x, tileN = blockIdx.y, tileM = blockIdx.z;
  const bf16_t* A = Hbuf + ((size_t)e * MPAD + tileM * 64) * HH;
  const bf16_t* B = W2t + ((size_t)e * DD + tileN * 128) * HH;
  f32x4 acc[4][2];
  const f32x4 z = {0.f, 0.f, 0.f, 0.f};
#pragma unroll
  for (int j = 0; j < 4; ++j)
#pragma unroll
    for (int i = 0; i < 2; ++i) acc[j][i] = z;
  gemm_core<2, HH, HH>(A, B, As, Bs, acc);

  const int tid = threadIdx.x, wave = tid >> 6, lane = tid & 63;
  const int mw = (wave >> 1) * 32, nw = (wave & 1) * 64;
  const int l15 = lane & 15, quad = lane >> 4;
  const int nk = kept[e];
#pragma unroll
  for (int j = 0; j < 4; ++j) {
    const int n0 = tileN * 128 + nw + j * 16 + quad * 4;   // 4 consecutive n
#pragma unroll
    for (int i = 0; i < 2; ++i) {
      const int m = tileM * 64 + mw + i * 16 + l15;
      if (m < nk) {
        bf16x4 o4;
        o4.x = tobf(acc[j][i][0]);
        o4.y = tobf(acc[j][i][1]);
        o4.z = tobf(acc[j][i][2]);
        o4.w = tobf(acc[j][i][3]);
        *(bf16x4*)(Ybuf + ((size_t)e * MPAD + m) * DD + n0) = o4;  // 8B store
      }
    }
  }
}

// ---------------- combine: out[t] = sum_k w_k * (Ybuf[slot_k] + b2[e_k]) ------
__global__ __launch_bounds__(128) void combine_kernel(
    const bf16_t* __restrict__ Ybuf, const float* __restrict__ b2,
    const int* __restrict__ slot_map, const float* __restrict__ top_g,
    float* __restrict__ out) {
  const int t = blockIdx.x;
  const int c = threadIdx.x * 4;
  float4 acc = {0.f, 0.f, 0.f, 0.f};
#pragma unroll
  for (int k = 0; k < 2; ++k) {
    const int sm = slot_map[k * TT + t];
    if (sm >= 0) {                       // block-uniform branch
      const int e = sm >> 16, pos = sm & 0xFFFF;
      const float w = top_g[t * 2 + k];
      const bf16x4 y4 = *(const bf16x4*)(Ybuf + ((size_t)e * MPAD + pos) * DD + c);
      const float4 bb = *(const float4*)(b2 + e * DD + c);
      acc.x += w * ((float)y4.x + bb.x);
      acc.y += w * ((float)y4.y + bb.y);
      acc.z += w * ((float)y4.z + bb.z);
      acc.w += w * ((float)y4.w + bb.w);
    }
  }
  *(float4*)(out + (size_t)t * DD + c) = acc;
}

// ---------------- launch ----------------
extern "C" void kernel_launch(void* const* d_in, const int* in_sizes, int n_in,
                              void* d_out, int out_size, void* d_ws, size_t ws_size,
                              hipStream_t stream) {
  const float* x      = (const float*)d_in[0];
  const float* gate_w = (const float*)d_in[1];
  const float* fc1_w  = (const float*)d_in[2];
  const float* fc1_b  = (const float*)d_in[3];
  const float* fc2_w  = (const float*)d_in[4];
  const float* fc2_b  = (const float*)d_in[5];
  float* out = (float*)d_out;

  char* ws = (char*)d_ws;
  float*  imp   = (float*)(ws + 0);
  int*    kept  = (int*)(ws + 64);
  int*    top_i = (int*)(ws + OFF_TOPI);
  float*  top_g = (float*)(ws + OFF_TOPG);
  int*    slotm = (int*)(ws + OFF_SLOT);
  int*    etok  = (int*)(ws + OFF_ETOK);
  float*  ewt   = (float*)(ws + OFF_EWT);
  bf16_t* Xg    = (bf16_t*)(ws + OFF_XG);
  bf16_t* W1t   = (bf16_t*)(ws + OFF_W1T);
  bf16_t* W2t   = (bf16_t*)(ws + OFF_W2T);
  bf16_t* Hbuf  = (bf16_t*)(ws + OFF_H);
  bf16_t* Ybuf  = (bf16_t*)(ws + OFF_Y);    // aliases Xg (dead after gemm1)
  float*  scal  = out + (size_t)TT * DD;

  hipMemsetAsync(ws, 0, 256, stream);       // imp atomic base

  transpose_both_kernel<<<dim3(32, 8, 16), 256, 0, stream>>>(fc1_w, W1t, fc2_w, W2t);

  void* args[] = {(void*)&x, (void*)&gate_w, (void*)&imp, (void*)&top_i,
                  (void*)&top_g, (void*)&etok, (void*)&ewt, (void*)&slotm,
                  (void*)&kept, (void*)&scal, (void*)&Xg};
  hipLaunchCooperativeKernel((void*)prep_kernel, dim3(256), dim3(1024), args, 0, stream);

  // blockIdx.x = expert -> XCD affinity (id % 8 round-robin heuristic)
  gemm1_kernel<<<dim3(E_, HH / 128, MT), 256, 0, stream>>>(Xg, W1t, fc1_b, Hbuf);
  gemm2_kernel<<<dim3(E_, DD / 128, MT2), 256, 0, stream>>>(Hbuf, W2t, kept, Ybuf);
  combine_kernel<<<TT, 128, 0, stream>>>(Ybuf, fc2_b, slotm, top_g, out);
}

// Round 11
// 226.682 us; speedup vs baseline: 1.2510x; 1.2510x over previous
//
#include <hip/hip_runtime.h>
#include <hip/hip_bf16.h>

// ---------------- problem constants ----------------
#define E_    8
#define TT    4096      // tokens = B*S
#define DD    512
#define HH    2048
#define CAP   1075      // round(2*4096*1.05/8)
#define MPAD  1152      // 9 * 128, padded rows per expert
#define MT    9         // 128-row M tiles per expert (gemm1)
#define MT2   18        // 64-row M tiles per expert (gemm2)

typedef __bf16 bf16_t;
typedef bf16_t bf16x4 __attribute__((ext_vector_type(4)));
typedef bf16_t bf16x8 __attribute__((ext_vector_type(8)));
typedef float  f32x4  __attribute__((ext_vector_type(4)));
typedef unsigned int u32;

__device__ __forceinline__ bf16_t tobf(float f) { return (bf16_t)f; }  // fptrunc, RNE

// tanh-form gelu: max |diff vs erf-gelu| ~3e-4 in h; through fc2's random-sign
// weights adds ~2e-4 to y (threshold 4.97e-2). exp overflow-safe via |u|+copysign.
__device__ __forceinline__ float gelu_f(float v) {
  const float u = v * (0.7978845608028654f + 0.035677408136300125f * v * v);
  const float a = __builtin_fabsf(u);
  const float ex = __expf(2.0f * a);
  float th = 1.0f - 2.0f / (ex + 1.0f);
  th = __builtin_copysignf(th, u);
  return 0.5f * v * (1.0f + th);
}

// ---------------- workspace layout (bytes) ----------------
// hdr: imp[8] f32 @0, kept[8] i32 @64
#define OFF_TOPI  256u
#define OFF_TOPG  (OFF_TOPI + 4096u*2u*4u)
#define OFF_SLOT  (OFF_TOPG + 4096u*2u*4u)            // slot_map[2*T] i32
#define OFF_ETOK  (OFF_SLOT + 4096u*2u*4u)
#define OFF_EWT   (OFF_ETOK + 8u*1152u*4u)
#define OFF_XG    (OFF_EWT  + 8u*1152u*4u)            // 16B aligned
#define XG_BYTES  (8u*1152u*512u*2u)                  // 9,437,184
#define OFF_W1T   (OFF_XG + XG_BYTES)
#define W1T_BYTES (8u*512u*2048u*2u)                  // 16,777,216
#define OFF_W2T   (OFF_W1T + W1T_BYTES)
#define W2T_BYTES (8u*2048u*512u*2u)                  // 16,777,216
#define OFF_H     (OFF_W2T + W2T_BYTES)
#define H_BYTES   (8u*1152u*2048u*2u)                 // 37,748,736
// Ybuf bf16 [E][MPAD][DD] = 9,437,184 B ALIASES Xg (dead after gemm1).
#define OFF_Y     OFF_XG
// total ~80.9 MB
//
// SESSION LESSONS (r0-r10, MI355X):
//  - split-K fp32 atomics: 4x atomic traffic, -37% (r2). Pure GEMM + gather
//    combine wins.
//  - LDS XOR swizzle on global-side of global_load_lds: conflicts 7.1M -> 0.
//  - C^T (swapped MFMA operands): packed 8B epilogue stores, +6%.
//  - blockIdx.x=expert XCD affinity: FETCH 46->21 MB.
//  - occupancy 3 vs 4 blocks/CU: neutral — gemm1 is barrier-drain bound, not
//    occupancy bound (2-barrier K-loop plateau, m97-class).
//  - B-LDS double-buffer + direct-global A frags: 2x REGRESSION (r9) — A frags
//    from global = 1KB-stride lane gather; A must round-trip through LDS.
//  - cooperative fusion of prep phases: 3x REGRESSION (r6/r7/r10) — grid.sync
//    costs ~20us each here, more than the launch gaps it removes.

// ---------------- router: logits, softmax, top-2, imp ----------------
__global__ __launch_bounds__(256) void router_kernel(
    const float* __restrict__ x, const float* __restrict__ gw,
    float* __restrict__ imp, int* __restrict__ top_i, float* __restrict__ top_g) {
  const int tid = threadIdx.x;
  const int wid = tid >> 6, lane = tid & 63;
  const int t = blockIdx.x * 4 + wid;

  float p[E_];
#pragma unroll
  for (int e = 0; e < E_; ++e) p[e] = 0.f;
  const float* xr = x + (size_t)t * DD;
#pragma unroll
  for (int it = 0; it < DD / 64; ++it) {
    const int d = it * 64 + lane;
    const float xv = xr[d];
#pragma unroll
    for (int e = 0; e < E_; ++e) p[e] += xv * gw[e * DD + d];
  }
#pragma unroll
  for (int off = 32; off > 0; off >>= 1) {
#pragma unroll
    for (int e = 0; e < E_; ++e) p[e] += __shfl_down(p[e], off);
  }

  __shared__ float simp[4][E_];
  if (lane == 0) {
    float mx = p[0];
#pragma unroll
    for (int e = 1; e < E_; ++e) mx = fmaxf(mx, p[e]);
    float g[E_]; float s = 0.f;
#pragma unroll
    for (int e = 0; e < E_; ++e) { g[e] = expf(p[e] - mx); s += g[e]; }
    const float inv = 1.f / s;
#pragma unroll
    for (int e = 0; e < E_; ++e) { g[e] *= inv; simp[wid][e] = g[e]; }
    // top-2, ties -> lowest index (matches jax.lax.top_k)
    int i0 = 0;
#pragma unroll
    for (int e = 1; e < E_; ++e) if (g[e] > g[i0]) i0 = e;
    int i1 = (i0 == 0) ? 1 : 0;
#pragma unroll
    for (int e = 0; e < E_; ++e) if (e != i0 && g[e] > g[i1]) i1 = e;
    top_i[t * 2 + 0] = i0;  top_i[t * 2 + 1] = i1;
    top_g[t * 2 + 0] = g[i0]; top_g[t * 2 + 1] = g[i1];
  }
  __syncthreads();
  if (tid < E_) {
    const float s = simp[0][tid] + simp[1][tid] + simp[2][tid] + simp[3][tid];
    atomicAdd(&imp[tid], s);
  }
}

// ---------------- capacity: packed shfl scan + dispatch + slot_map + scalars --
__global__ __launch_bounds__(1024) void capacity_kernel(
    const int* __restrict__ top_i, const float* __restrict__ top_g,
    const float* __restrict__ imp, int* __restrict__ etok, float* __restrict__ ewt,
    int* __restrict__ slot_map, int* __restrict__ kept, float* __restrict__ scal) {
  __shared__ u32 wt[16][4];
  const int tid = threadIdx.x, wave = tid >> 6, lane = tid & 63;

  int eidx[8];
#pragma unroll
  for (int q = 0; q < 8; ++q) {
    const int j = tid * 8 + q;          // slot-major: j = k*T + t
    const int k = j >> 12, t = j & (TT - 1);
    eidx[q] = top_i[t * 2 + k];
  }
  u32 pk[4] = {0u, 0u, 0u, 0u};
#pragma unroll
  for (int q = 0; q < 8; ++q) pk[eidx[q] >> 1] += 1u << ((eidx[q] & 1) * 16);

  u32 v[4] = {pk[0], pk[1], pk[2], pk[3]};   // inclusive wave scan
#pragma unroll
  for (int off = 1; off < 64; off <<= 1) {
#pragma unroll
    for (int p = 0; p < 4; ++p) {
      const u32 n = (u32)__shfl_up((int)v[p], off);
      if (lane >= off) v[p] += n;
    }
  }
  if (lane == 63) {
#pragma unroll
    for (int p = 0; p < 4; ++p) wt[wave][p] = v[p];
  }
  __syncthreads();
  u32 base[4] = {0u, 0u, 0u, 0u}, tot[4] = {0u, 0u, 0u, 0u};
#pragma unroll
  for (int w = 0; w < 16; ++w) {
#pragma unroll
    for (int p = 0; p < 4; ++p) {
      const u32 xv = wt[w][p];
      if (w < wave) base[p] += xv;
      tot[p] += xv;
    }
  }
  int run[E_];
#pragma unroll
  for (int p = 0; p < 4; ++p) {
    const u32 excl = base[p] + v[p] - pk[p];    // exclusive thread prefix
    run[2 * p]     = (int)(excl & 0xFFFFu);
    run[2 * p + 1] = (int)(excl >> 16);
  }
#pragma unroll
  for (int q = 0; q < 8; ++q) {
    const int e = eidx[q];
    const int pos = run[e]++;           // counts ALL earlier same-expert entries
    const int j = tid * 8 + q;
    if (pos < CAP) {
      const int k = j >> 12, t = j & (TT - 1);
      etok[e * MPAD + pos] = t;
      ewt[e * MPAD + pos] = top_g[t * 2 + k];
      slot_map[j] = (e << 16) | pos;
    } else {
      slot_map[j] = -1;
    }
  }
  if (tid == 0) {
    float tpe[E_];
#pragma unroll
    for (int p = 0; p < 4; ++p) {
      const int t0 = (int)(tot[p] & 0xFFFFu), t1 = (int)(tot[p] >> 16);
      const int k0 = t0 < CAP ? t0 : CAP, k1 = t1 < CAP ? t1 : CAP;
      kept[2 * p] = k0; kept[2 * p + 1] = k1;
      tpe[2 * p] = (float)k0; tpe[2 * p + 1] = (float)k1;
    }
    float ms = 0.f;
#pragma unroll
    for (int e = 0; e < E_; ++e) ms += tpe[e];
    ms *= (1.f / E_);
    float vt = 0.f;
#pragma unroll
    for (int e = 0; e < E_; ++e) { const float d = tpe[e] - ms; vt += d * d; }
    vt *= (1.f / E_);
    const float ll = vt / ((ms + 1e-6f) * (ms + 1e-6f));

    float iv[E_], mi = 0.f;
#pragma unroll
    for (int e = 0; e < E_; ++e) { iv[e] = imp[e]; mi += iv[e]; }
    mi *= (1.f / E_);
    float vi = 0.f;
#pragma unroll
    for (int e = 0; e < E_; ++e) { const float d = iv[e] - mi; vi += d * d; }
    vi *= (1.f / E_);
    const float il = vi / ((mi + 1e-6f) * (mi + 1e-6f));

    scal[0] = 0.5f * (il + ll);   // l_aux
    scal[1] = ll;                 // l_load
  }
}

// ---------------- gather x rows -> bf16 per-expert buffers ----------------
// Pad rows (m >= kept[e]) stay 0xAA poison: finite bf16; everything derived
// from them is discarded (gemm2 epilogue guard + combine reads kept slots only).
__global__ __launch_bounds__(256) void gather_kernel(
    const float* __restrict__ x, const int* __restrict__ etok,
    const int* __restrict__ kept, bf16_t* __restrict__ Xg) {
  const int e = blockIdx.y, wid = threadIdx.x >> 6, lane = threadIdx.x & 63;
  const int m = blockIdx.x * 4 + wid;
  if (m >= kept[e]) return;
  const int t = etok[e * MPAD + m];
  const float* src = x + (size_t)t * DD + lane * 8;
  const float4 a = *(const float4*)src;
  const float4 b = *(const float4*)(src + 4);
  bf16_t tmp[8] = {tobf(a.x), tobf(a.y), tobf(a.z), tobf(a.w),
                   tobf(b.x), tobf(b.y), tobf(b.z), tobf(b.w)};
  *(bf16x8*)(Xg + ((size_t)e * MPAD + m) * DD + lane * 8) = *(const bf16x8*)tmp;
}

// ---------------- merged weight transpose+cast, vectorized stores -------------
// 64x64 f32 tile -> bf16x4 (8B) packed stores. LDS 64x65 pad (2-way = free).
// z<8: fc1 [512][2048]->[2048][512]; z>=8: fc2 [2048][512]->[512][2048].
__global__ __launch_bounds__(256) void transpose_both_kernel(
    const float* __restrict__ fc1, bf16_t* __restrict__ w1t,
    const float* __restrict__ fc2, bf16_t* __restrict__ w2t) {
  __shared__ float tile[64][65];
  const int z = blockIdx.z;
  const bool first = (z < 8);
  const int e = first ? z : z - 8;
  const int R = first ? DD : HH;
  const int C = first ? HH : DD;
  const int ct = first ? blockIdx.x : blockIdx.y;   // C/64 tiles
  const int rt = first ? blockIdx.y : blockIdx.x;   // R/64 tiles
  const float* ip = (first ? fc1 : fc2) + (size_t)e * DD * HH;
  bf16_t* op = (first ? w1t : w2t) + (size_t)e * DD * HH;
  const int r0 = rt * 64, c0 = ct * 64;
  const int tid = threadIdx.x;
  const int rr = tid >> 6, cc = tid & 63;           // read: 4 rows/pass, 64 cols
#pragma unroll
  for (int p = 0; p < 16; ++p)
    tile[p * 4 + rr][cc] = ip[(size_t)(r0 + p * 4 + rr) * C + c0 + cc];
  __syncthreads();
  const int g = tid & 15, ob = tid >> 4;            // write: col-group, row-base
#pragma unroll
  for (int p = 0; p < 4; ++p) {
    const int oc = p * 16 + ob;
    bf16x4 o4;
    o4.x = tobf(tile[g * 4 + 0][oc]);
    o4.y = tobf(tile[g * 4 + 1][oc]);
    o4.z = tobf(tile[g * 4 + 2][oc]);
    o4.w = tobf(tile[g * 4 + 3][oc]);
    *(bf16x4*)(op + (size_t)(c0 + oc) * R + r0 + g * 4) = o4;
  }
}

// ---------------- TN GEMM core (r8, proven): C^T via swapped MFMA operands ----
// A: [MI*32 rows][KSTR] bf16, B: [128 cols][KSTR] bf16 (pre-transposed).
// acc[j][i] = mfma(bfr[j], af[i], acc) -> transposed tile: lane&15 -> m,
// quad*4+reg -> n, so each thread owns 4 CONSECUTIVE n -> packed stores.
// Both operands staged via global_load_lds width=16 (coalesced); LDS 16B-chunk
// XOR swizzle applied on the GLOBAL-side address; read side XORs with l15&7.
template <int MI, int KLEN, int KSTR>
__device__ __forceinline__ void gemm_core(
    const bf16_t* __restrict__ A, const bf16_t* __restrict__ B,
    bf16_t* As, bf16_t* Bs, f32x4 (&acc)[4][MI]) {
  const int tid = threadIdx.x;
  const int wave = tid >> 6, lane = tid & 63;
  const int r8 = lane >> 3;                       // row within 8-row group
  const int kswz = ((lane & 7) ^ r8) * 8;         // swizzled k-offset (elements)
  const bf16_t* ga = A + (size_t)(wave * (MI * 8) + r8) * KSTR + kswz;
  const bf16_t* gb = B + (size_t)(wave * 32 + r8) * KSTR + kswz;
  const int mw = (wave >> 1) * (MI * 16), nw = (wave & 1) * 64;
  const int l15 = lane & 15, quad = lane >> 4;
  const int sw = l15 & 7;                         // read-side swizzle key

  for (int k0 = 0; k0 < KLEN; k0 += 64) {
    __syncthreads();   // protect LDS from overwrite while prior chunk computes
#pragma unroll
    for (int p = 0; p < MI; ++p) {
      __builtin_amdgcn_global_load_lds(
          (const __attribute__((address_space(1))) void*)(ga + (size_t)p * 8 * KSTR + k0),
          (__attribute__((address_space(3))) void*)(As + (wave * (MI * 8) + p * 8) * 64),
          16, 0, 0);
    }
#pragma unroll
    for (int p = 0; p < 4; ++p) {
      __builtin_amdgcn_global_load_lds(
          (const __attribute__((address_space(1))) void*)(gb + (size_t)p * 8 * KSTR + k0),
          (__attribute__((address_space(3))) void*)(Bs + (wave * 32 + p * 8) * 64),
          16, 0, 0);
    }
    __syncthreads();   // drains vmcnt before compute
#pragma unroll
    for (int ks = 0; ks < 2; ++ks) {
      bf16x8 af[MI], bfr[4];
#pragma unroll
      for (int i = 0; i < MI; ++i)
        af[i] = *(const bf16x8*)(As + (mw + i * 16 + l15) * 64 + (((ks * 4 + quad) ^ sw) << 3));
#pragma unroll
      for (int j = 0; j < 4; ++j)
        bfr[j] = *(const bf16x8*)(Bs + (nw + j * 16 + l15) * 64 + (((ks * 4 + quad) ^ sw) << 3));
#pragma unroll
      for (int j = 0; j < 4; ++j)
#pragma unroll
        for (int i = 0; i < MI; ++i)
          acc[j][i] = __builtin_amdgcn_mfma_f32_16x16x32_bf16(bfr[j], af[i], acc[j][i], 0, 0, 0);
    }
  }
}

// ---------------- GEMM1: H = gelu(Xg @ W1 + b1), bf16 out, 128x128 tile ------
// blockIdx.x = expert -> XCD (id%8): each XCD's window touches one expert's
// B tiles (~2 MB, L2-resident; verified FETCH 46->21 MB in r5).
__global__ __launch_bounds__(256, 4) void gemm1_kernel(
    const bf16_t* __restrict__ Xg, const bf16_t* __restrict__ W1t,
    const float* __restrict__ b1, bf16_t* __restrict__ Hbuf) {
  __shared__ __align__(16) bf16_t As[128 * 64];
  __shared__ __align__(16) bf16_t Bs[128 * 64];
  const int e = blockIdx.x, tileN = blockIdx.y, tileM = blockIdx.z;
  const bf16_t* A = Xg + ((size_t)e * MPAD + tileM * 128) * DD;
  const bf16_t* B = W1t + ((size_t)e * HH + tileN * 128) * DD;
  f32x4 acc[4][4];
  const f32x4 z = {0.f, 0.f, 0.f, 0.f};
#pragma unroll
  for (int j = 0; j < 4; ++j)
#pragma unroll
    for (int i = 0; i < 4; ++i) acc[j][i] = z;
  gemm_core<4, DD, DD>(A, B, As, Bs, acc);

  const int tid = threadIdx.x, wave = tid >> 6, lane = tid & 63;
  const int mw = (wave >> 1) * 64, nw = (wave & 1) * 64;
  const int l15 = lane & 15, quad = lane >> 4;
#pragma unroll
  for (int j = 0; j < 4; ++j) {
    const int n0 = tileN * 128 + nw + j * 16 + quad * 4;   // 4 consecutive n
    const float4 b4 = *(const float4*)(b1 + e * HH + n0);
#pragma unroll
    for (int i = 0; i < 4; ++i) {
      const int m = tileM * 128 + mw + i * 16 + l15;
      bf16x4 h4;
      h4.x = tobf(gelu_f(acc[j][i][0] + b4.x));
      h4.y = tobf(gelu_f(acc[j][i][1] + b4.y));
      h4.z = tobf(gelu_f(acc[j][i][2] + b4.z));
      h4.w = tobf(gelu_f(acc[j][i][3] + b4.w));
      *(bf16x4*)(Hbuf + ((size_t)e * MPAD + m) * HH + n0) = h4;   // 8B store
    }
  }
}

// ---------------- GEMM2: Ybuf = H @ W2 (bf16 out), 64x128 tile ---------------
__global__ __launch_bounds__(256, 6) void gemm2_kernel(
    const bf16_t* __restrict__ Hbuf, const bf16_t* __restrict__ W2t,
    const int* __restrict__ kept, bf16_t* __restrict__ Ybuf) {
  __shared__ __align__(16) bf16_t As[64 * 64];    // 8 KB
  __shared__ __align__(16) bf16_t Bs[128 * 64];   // 16 KB
  const int e = blockIdx.x, tileN = blockIdx.y, tileM = blockIdx.z;
  const bf16_t* A = Hbuf + ((size_t)e * MPAD + tileM * 64) * HH;
  const bf16_t* B = W2t + ((size_t)e * DD + tileN * 128) * HH;
  f32x4 acc[4][2];
  const f32x4 z = {0.f, 0.f, 0.f, 0.f};
#pragma unroll
  for (int j = 0; j < 4; ++j)
#pragma unroll
    for (int i = 0; i < 2; ++i) acc[j][i] = z;
  gemm_core<2, HH, HH>(A, B, As, Bs, acc);

  const int tid = threadIdx.x, wave = tid >> 6, lane = tid & 63;
  const int mw = (wave >> 1) * 32, nw = (wave & 1) * 64;
  const int l15 = lane & 15, quad = lane >> 4;
  const int nk = kept[e];
#pragma unroll
  for (int j = 0; j < 4; ++j) {
    const int n0 = tileN * 128 + nw + j * 16 + quad * 4;   // 4 consecutive n
#pragma unroll
    for (int i = 0; i < 2; ++i) {
      const int m = tileM * 64 + mw + i * 16 + l15;
      if (m < nk) {
        bf16x4 o4;
        o4.x = tobf(acc[j][i][0]);
        o4.y = tobf(acc[j][i][1]);
        o4.z = tobf(acc[j][i][2]);
        o4.w = tobf(acc[j][i][3]);
        *(bf16x4*)(Ybuf + ((size_t)e * MPAD + m) * DD + n0) = o4;  // 8B store
      }
    }
  }
}

// ---------------- combine: out[t] = sum_k w_k * (Ybuf[slot_k] + b2[e_k]) ------
__global__ __launch_bounds__(128) void combine_kernel(
    const bf16_t* __restrict__ Ybuf, const float* __restrict__ b2,
    const int* __restrict__ slot_map, const float* __restrict__ top_g,
    float* __restrict__ out) {
  const int t = blockIdx.x;
  const int c = threadIdx.x * 4;
  float4 acc = {0.f, 0.f, 0.f, 0.f};
#pragma unroll
  for (int k = 0; k < 2; ++k) {
    const int sm = slot_map[k * TT + t];
    if (sm >= 0) {                       // block-uniform branch
      const int e = sm >> 16, pos = sm & 0xFFFF;
      const float w = top_g[t * 2 + k];
      const bf16x4 y4 = *(const bf16x4*)(Ybuf + ((size_t)e * MPAD + pos) * DD + c);
      const float4 bb = *(const float4*)(b2 + e * DD + c);
      acc.x += w * ((float)y4.x + bb.x);
      acc.y += w * ((float)y4.y + bb.y);
      acc.z += w * ((float)y4.z + bb.z);
      acc.w += w * ((float)y4.w + bb.w);
    }
  }
  *(float4*)(out + (size_t)t * DD + c) = acc;
}

// ---------------- launch ----------------
extern "C" void kernel_launch(void* const* d_in, const int* in_sizes, int n_in,
                              void* d_out, int out_size, void* d_ws, size_t ws_size,
                              hipStream_t stream) {
  const float* x      = (const float*)d_in[0];
  const float* gate_w = (const float*)d_in[1];
  const float* fc1_w  = (const float*)d_in[2];
  const float* fc1_b  = (const float*)d_in[3];
  const float* fc2_w  = (const float*)d_in[4];
  const float* fc2_b  = (const float*)d_in[5];
  float* out = (float*)d_out;

  char* ws = (char*)d_ws;
  float*  imp   = (float*)(ws + 0);
  int*    kept  = (int*)(ws + 64);
  int*    top_i = (int*)(ws + OFF_TOPI);
  float*  top_g = (float*)(ws + OFF_TOPG);
  int*    slotm = (int*)(ws + OFF_SLOT);
  int*    etok  = (int*)(ws + OFF_ETOK);
  float*  ewt   = (float*)(ws + OFF_EWT);
  bf16_t* Xg    = (bf16_t*)(ws + OFF_XG);
  bf16_t* W1t   = (bf16_t*)(ws + OFF_W1T);
  bf16_t* W2t   = (bf16_t*)(ws + OFF_W2T);
  bf16_t* Hbuf  = (bf16_t*)(ws + OFF_H);
  bf16_t* Ybuf  = (bf16_t*)(ws + OFF_Y);    // aliases Xg (dead after gemm1)
  float*  scal  = out + (size_t)TT * DD;

  hipMemsetAsync(ws, 0, 256, stream);       // imp atomic base

  transpose_both_kernel<<<dim3(32, 8, 16), 256, 0, stream>>>(fc1_w, W1t, fc2_w, W2t);

  router_kernel<<<TT / 4, 256, 0, stream>>>(x, gate_w, imp, top_i, top_g);
  capacity_kernel<<<1, 1024, 0, stream>>>(top_i, top_g, imp, etok, ewt, slotm, kept, scal);
  gather_kernel<<<dim3(MPAD / 4, E_), 256, 0, stream>>>(x, etok, kept, Xg);

  // blockIdx.x = expert -> XCD affinity (id % 8 round-robin heuristic)
  gemm1_kernel<<<dim3(E_, HH / 128, MT), 256, 0, stream>>>(Xg, W1t, fc1_b, Hbuf);
  gemm2_kernel<<<dim3(E_, DD / 128, MT2), 256, 0, stream>>>(Hbuf, W2t, kept, Ybuf);
  combine_kernel<<<TT, 128, 0, stream>>>(Ybuf, fc2_b, slotm, top_g, out);
}